// Round 5
// baseline (314.649 us; speedup 1.0000x reference)
//
#include <hip/hip_runtime.h>
#include <math.h>

#define B_   128
#define R_   1152
#define C_   16
#define O_   16
#define RS_  64
#define RCH_ 18            // R_/RS_

// ws float offsets: blog | s0 | s1 | s2
#define WS_BLOG 0          // 18432
#define WS_S0   18432      // 32768
#define WS_S1   51200      // 32768
#define WS_S2   83968      // 32768

__device__ __forceinline__ float squashf(float s) {
    return s * fabsf(s) / (1.0f + s * s);
}

// ---------- G: s[b,co] += sum_{r in chunk,i} x[b,r,i]*cw[r,c]*W[r,co,i] (atomic split-K)
// grid (8 bt, 64 rs) x 256. SOFTMAX: cw computed per-block from blog (redundant).
template <bool SOFTMAX>
__global__ __launch_bounds__(256) void gemm_s_k(const float* __restrict__ x,
                                                const float* __restrict__ W,
                                                const float* __restrict__ blog,
                                                float* __restrict__ s_out) {
    const int bt  = blockIdx.x;
    const int rs  = blockIdx.y;
    const int t   = threadIdx.x;
    const int co4 = t & 63;
    const int b4  = t >> 6;
    const int c   = co4 >> 2;
    const int r0  = rs * RCH_;

    __shared__ float4 xl4[16 * 36];   // 9 KB x-tile
    __shared__ float  red[256];
    __shared__ float  mcs[32];        // [0:16) col max, [16:32) 1/sum
    __shared__ float  cwl[288];       // cw for this block's 18 r x 16 c

    const float4* __restrict__ X4 = (const float4*)x;
    const float4* __restrict__ W4 = (const float4*)W;

    if (SOFTMAX) {
        const int pc = t & 15, seg = t >> 4;
        const float* bp = blog + pc;
        float m = -1e30f;
        #pragma unroll 8
        for (int k = 0; k < 72; ++k) m = fmaxf(m, bp[(seg * 72 + k) * 16]);
        red[t] = m; __syncthreads();
        #pragma unroll
        for (int s2 = 128; s2 >= 16; s2 >>= 1) {
            if (t < s2) red[t] = fmaxf(red[t], red[t + s2]);
            __syncthreads();
        }
        if (t < 16) mcs[t] = red[t];
        __syncthreads();
        const float Mc = mcs[pc];
        float e = 0.f;
        #pragma unroll 8
        for (int k = 0; k < 72; ++k) e += __expf(bp[(seg * 72 + k) * 16] - Mc);
        red[t] = e; __syncthreads();
        #pragma unroll
        for (int s2 = 128; s2 >= 16; s2 >>= 1) {
            if (t < s2) red[t] += red[t + s2];
            __syncthreads();
        }
        if (t < 16) mcs[16 + t] = 1.0f / red[t];
        __syncthreads();
        for (int u = t; u < 288; u += 256) {
            const int rl = u >> 4, cc = u & 15;
            cwl[u] = __expf(blog[(r0 + rl) * 16 + cc] - mcs[cc]) * mcs[16 + cc];
        }
    }

    // stage x[bt*16 + bl][r0..r0+17][0:8] -> 576 float4
    {
        int u = t;
        { const int bl = u / 36, rem = u % 36;
          xl4[u] = X4[((bt * 16 + bl) * R_ + r0) * 2 + rem]; }
        u = t + 256;
        { const int bl = u / 36, rem = u % 36;
          xl4[u] = X4[((bt * 16 + bl) * R_ + r0) * 2 + rem]; }
        u = t + 512;
        if (u < 576) {
            const int bl = u / 36, rem = u % 36;
            xl4[u] = X4[((bt * 16 + bl) * R_ + r0) * 2 + rem];
        }
    }
    __syncthreads();

    float acc[4][4];
    #pragma unroll
    for (int j = 0; j < 4; ++j)
        #pragma unroll
        for (int q = 0; q < 4; ++q) acc[j][q] = 0.f;

    #pragma unroll 2
    for (int rr = 0; rr < RCH_; ++rr) {
        const int r = r0 + rr;
        const float cwv = SOFTMAX ? cwl[rr * 16 + c] : (1.0f / (float)R_);
        const int wb = r * 512 + co4 * 8;
        const float4 w0 = W4[wb + 0], w1 = W4[wb + 1], w2 = W4[wb + 2], w3 = W4[wb + 3];
        const float4 w4 = W4[wb + 4], w5 = W4[wb + 5], w6 = W4[wb + 6], w7 = W4[wb + 7];
        #pragma unroll
        for (int j = 0; j < 4; ++j) {
            const float4 xa = xl4[(b4 * 4 + j) * 36 + rr * 2];
            const float4 xb = xl4[(b4 * 4 + j) * 36 + rr * 2 + 1];
            const float d0 = w0.x*xa.x + w0.y*xa.y + w0.z*xa.z + w0.w*xa.w
                           + w1.x*xb.x + w1.y*xb.y + w1.z*xb.z + w1.w*xb.w;
            const float d1 = w2.x*xa.x + w2.y*xa.y + w2.z*xa.z + w2.w*xa.w
                           + w3.x*xb.x + w3.y*xb.y + w3.z*xb.z + w3.w*xb.w;
            const float d2 = w4.x*xa.x + w4.y*xa.y + w4.z*xa.z + w4.w*xa.w
                           + w5.x*xb.x + w5.y*xb.y + w5.z*xb.z + w5.w*xb.w;
            const float d3 = w6.x*xa.x + w6.y*xa.y + w6.z*xa.z + w6.w*xa.w
                           + w7.x*xb.x + w7.y*xb.y + w7.z*xb.z + w7.w*xb.w;
            acc[j][0] = fmaf(cwv, d0, acc[j][0]);
            acc[j][1] = fmaf(cwv, d1, acc[j][1]);
            acc[j][2] = fmaf(cwv, d2, acc[j][2]);
            acc[j][3] = fmaf(cwv, d3, acc[j][3]);
        }
    }

    #pragma unroll
    for (int j = 0; j < 4; ++j) {
        float* dst = s_out + (bt * 16 + b4 * 4 + j) * 256 + co4 * 4;
        unsafeAtomicAdd(dst + 0, acc[j][0]);
        unsafeAtomicAdd(dst + 1, acc[j][1]);
        unsafeAtomicAdd(dst + 2, acc[j][2]);
        unsafeAtomicAdd(dst + 3, acc[j][3]);
    }
}

// ---------- A: blog[r,c] += (1/B) sum_{b,o} u_hat[b,r,co] * squash(s)[b,co]
// grid 1152 = 288 r-groups x 4 b-quarters; 512 thr = 8 waves (rr = w&3, bs = w>>2).
// Prepass: squash s-quarter into LDS (32 KB) once per block; also zero next s buffer.
__global__ __launch_bounds__(512) void a_k(const float* __restrict__ x,
                                           const float* __restrict__ W,
                                           const float* __restrict__ s_in,
                                           float* __restrict__ blog,
                                           float* __restrict__ s_zero) {
    const int blk = blockIdx.x;
    const int r0  = (blk >> 2) * 4;
    const int b0  = (blk & 3) * 32;
    const int t   = threadIdx.x;

    if (blk < 64 && t < 128) {
        float4 z; z.x = 0.f; z.y = 0.f; z.z = 0.f; z.w = 0.f;
        ((float4*)s_zero)[blk * 128 + t] = z;
    }

    __shared__ float4 vl[32 * 64];   // squash(s)[b0..b0+31][co4] = 32 KB
    __shared__ float4 xl[32 * 8];    // x[b0..b0+31][r0..r0+3][0:8] = 4 KB
    __shared__ float  red[128];

    const float4* __restrict__ S4 = (const float4*)s_in;
    const float4* __restrict__ X4 = (const float4*)x;
    const float4* __restrict__ W4 = (const float4*)W;

    #pragma unroll
    for (int u = t; u < 2048; u += 512) {
        const int bl = u >> 6, cc = u & 63;
        const float4 sv = S4[(b0 + bl) * 64 + cc];
        float4 vv;
        vv.x = squashf(sv.x); vv.y = squashf(sv.y);
        vv.z = squashf(sv.z); vv.w = squashf(sv.w);
        vl[u] = vv;
    }
    if (t < 256) {
        const int bl = t >> 3, rem = t & 7;
        xl[t] = X4[((b0 + bl) * R_ + r0) * 2 + rem];
    }
    __syncthreads();

    const int w = t >> 6, lane = t & 63;
    const int rr = w & 3, bs = w >> 2;
    const int co4 = lane, c = co4 >> 2;
    const int r = r0 + rr;

    float y[8][4];
    #pragma unroll
    for (int i = 0; i < 8; ++i)
        #pragma unroll
        for (int q = 0; q < 4; ++q) y[i][q] = 0.f;

    #pragma unroll 4
    for (int bb = 0; bb < 16; ++bb) {
        const int bl = bs * 16 + bb;
        const float4 xa = xl[bl * 8 + rr * 2];
        const float4 xb = xl[bl * 8 + rr * 2 + 1];
        const float4 vv = vl[bl * 64 + co4];
        const float xs[8] = {xa.x, xa.y, xa.z, xa.w, xb.x, xb.y, xb.z, xb.w};
        #pragma unroll
        for (int i = 0; i < 8; ++i) {
            y[i][0] = fmaf(xs[i], vv.x, y[i][0]);
            y[i][1] = fmaf(xs[i], vv.y, y[i][1]);
            y[i][2] = fmaf(xs[i], vv.z, y[i][2]);
            y[i][3] = fmaf(xs[i], vv.w, y[i][3]);
        }
    }

    // contract with W[r]: part = sum_{q,i} W[r, co4*4+q, i] * y[i][q]
    const int wb = r * 512 + co4 * 8;
    float part = 0.f;
    #pragma unroll
    for (int q = 0; q < 4; ++q) {
        const float4 w0 = W4[wb + q * 2];
        const float4 w1 = W4[wb + q * 2 + 1];
        part += w0.x*y[0][q] + w0.y*y[1][q] + w0.z*y[2][q] + w0.w*y[3][q]
              + w1.x*y[4][q] + w1.y*y[5][q] + w1.z*y[6][q] + w1.w*y[7][q];
    }
    part += __shfl_xor(part, 1);
    part += __shfl_xor(part, 2);
    if ((lane & 3) == 0) red[w * 16 + c] = part;
    __syncthreads();
    if (t < 64) {
        const int rr2 = t >> 4, cc = t & 15;
        const float sum = red[rr2 * 16 + cc] + red[(4 + rr2) * 16 + cc];
        unsafeAtomicAdd(&blog[(r0 + rr2) * 16 + cc], sum * (1.0f / (float)B_));
    }
}

// ---------- final: out = squash(s2), 32768 elems ----------
__global__ void squash_out_k(const float* __restrict__ s_in, float* __restrict__ out) {
    const int u = blockIdx.x * 256 + threadIdx.x;     // 8192 float4
    const float4 sv = ((const float4*)s_in)[u];
    float4 vv;
    vv.x = squashf(sv.x); vv.y = squashf(sv.y);
    vv.z = squashf(sv.z); vv.w = squashf(sv.w);
    ((float4*)out)[u] = vv;
}

extern "C" void kernel_launch(void* const* d_in, const int* in_sizes, int n_in,
                              void* d_out, int out_size, void* d_ws, size_t ws_size,
                              hipStream_t stream) {
    const float* x = (const float*)d_in[0];   // [128,1152,8]
    const float* W = (const float*)d_in[1];   // [1,1152,16,16,8]
    float* out = (float*)d_out;               // [128,16,16]
    float* ws  = (float*)d_ws;

    float* blog = ws + WS_BLOG;
    float* s0   = ws + WS_S0;
    float* s1   = ws + WS_S1;
    float* s2   = ws + WS_S2;

    // zero blog + s0 (contiguous)
    hipMemsetAsync(ws, 0, (size_t)(18432 + 32768) * sizeof(float), stream);

    gemm_s_k<false><<<dim3(8, RS_), 256, 0, stream>>>(x, W, blog, s0);
    a_k<<<1152, 512, 0, stream>>>(x, W, s0, blog, s1);
    gemm_s_k<true><<<dim3(8, RS_), 256, 0, stream>>>(x, W, blog, s1);
    a_k<<<1152, 512, 0, stream>>>(x, W, s1, blog, s2);
    gemm_s_k<true><<<dim3(8, RS_), 256, 0, stream>>>(x, W, blog, s2);
    squash_out_k<<<32, 256, 0, stream>>>(s2, out);
}

// Round 6
// 261.041 us; speedup vs baseline: 1.2054x; 1.2054x over previous
//
#include <hip/hip_runtime.h>
#include <math.h>

#define B_   128
#define R_   1152
#define C_   16
#define O_   16
#define RS_  128
#define RCH_ 9             // R_/RS_

// ws float offsets
#define WS_SP 0            // RS_*32768 = 4194304
#define WS_V  4194304      // 32768
#define WS_AB 4227072      // 4*18432 (ab[h][c][r], h=0,1 from iter0; h=2,3 from iter1)

__device__ __forceinline__ float squashf(float s) {
    return s * fabsf(s) / (1.0f + s * s);
}

// ---------- G: sp[rs][b][co] = sum_{r in chunk,i} x[b,r,i]*cw[r,c]*W[r,co,i]
// grid (8 bt, RS_ rs) x 256. NH=0: cw = 1/R (iter 0). NH>0: column softmax of
// blog[r,c] = (1/B) * sum_{h<NH} AB[h][c][r], computed redundantly per block.
template <int NH>
__global__ __launch_bounds__(256) void gemm_s_k(const float* __restrict__ x,
                                                const float* __restrict__ W,
                                                const float* __restrict__ AB,
                                                float* __restrict__ sp) {
    const int bt  = blockIdx.x;
    const int rs  = blockIdx.y;
    const int t   = threadIdx.x;
    const int co4 = t & 63;
    const int b4  = t >> 6;
    const int c   = co4 >> 2;
    const int r0  = rs * RCH_;

    __shared__ float4 xl4[16 * 2 * RCH_];   // 288 float4 = 4.6 KB
    __shared__ float  mcs[32];              // [0:16) col max (unscaled), [16:32) 1/sumexp
    __shared__ float  cwl[RCH_ * 16];       // softmax weights for this block's rows

    const float4* __restrict__ X4 = (const float4*)x;
    const float4* __restrict__ W4 = (const float4*)W;

    // ---- issue x staging loads early (hide under prepass) ----
    float4 xr0, xr1;
    {
        const int u0 = t;                       // 0..255
        const int bl0 = u0 / 18, rem0 = u0 % 18;
        xr0 = X4[((bt * 16 + bl0) * R_ + r0) * 2 + rem0];
        if (t < 32) {
            const int u1 = t + 256;
            const int bl1 = u1 / 18, rem1 = u1 % 18;
            xr1 = X4[((bt * 16 + bl1) * R_ + r0) * 2 + rem1];
        }
    }

    // ---- softmax prepass (redundant per block, data is L2-hot) ----
    if (NH > 0) {
        const int cg = t >> 4, li = t & 15;     // 16 threads per column
        const float* col = AB + cg * R_ + li;
        float m = -1e30f;
        #pragma unroll 4
        for (int k = 0; k < 72; ++k) {
            float s = 0.f;
            #pragma unroll
            for (int h = 0; h < NH; ++h) s += col[h * (C_ * R_) + k * 16];
            m = fmaxf(m, s);
        }
        #pragma unroll
        for (int d = 1; d < 16; d <<= 1) m = fmaxf(m, __shfl_xor(m, d));
        if (li == 0) mcs[cg] = m;
        __syncthreads();
        const float Mc = mcs[cg];
        float e = 0.f;
        #pragma unroll 4
        for (int k = 0; k < 72; ++k) {
            float s = 0.f;
            #pragma unroll
            for (int h = 0; h < NH; ++h) s += col[h * (C_ * R_) + k * 16];
            e += __expf((s - Mc) * (1.0f / (float)B_));
        }
        #pragma unroll
        for (int d = 1; d < 16; d <<= 1) e += __shfl_xor(e, d);
        if (li == 0) mcs[16 + cg] = 1.0f / e;
        __syncthreads();
        if (t < RCH_ * 16) {
            const int rl = t >> 4, cc = t & 15;
            float s = 0.f;
            #pragma unroll
            for (int h = 0; h < NH; ++h) s += AB[h * (C_ * R_) + cc * R_ + r0 + rl];
            cwl[t] = __expf((s - mcs[cc]) * (1.0f / (float)B_)) * mcs[16 + cc];
        }
    }

    // ---- commit x staging ----
    xl4[t] = xr0;
    if (t < 32) xl4[t + 256] = xr1;
    __syncthreads();

    float acc[4][4];
    #pragma unroll
    for (int j = 0; j < 4; ++j)
        #pragma unroll
        for (int q = 0; q < 4; ++q) acc[j][q] = 0.f;

    #pragma unroll 3
    for (int rr = 0; rr < RCH_; ++rr) {
        const float cwv = (NH > 0) ? cwl[rr * 16 + c] : (1.0f / (float)R_);
        const int wb = (r0 + rr) * 512 + co4 * 8;
        const float4 w0 = W4[wb + 0], w1 = W4[wb + 1], w2 = W4[wb + 2], w3 = W4[wb + 3];
        const float4 w4 = W4[wb + 4], w5 = W4[wb + 5], w6 = W4[wb + 6], w7 = W4[wb + 7];
        #pragma unroll
        for (int j = 0; j < 4; ++j) {
            const float4 xa = xl4[(b4 * 4 + j) * 18 + rr * 2];
            const float4 xb = xl4[(b4 * 4 + j) * 18 + rr * 2 + 1];
            const float d0 = w0.x*xa.x + w0.y*xa.y + w0.z*xa.z + w0.w*xa.w
                           + w1.x*xb.x + w1.y*xb.y + w1.z*xb.z + w1.w*xb.w;
            const float d1 = w2.x*xa.x + w2.y*xa.y + w2.z*xa.z + w2.w*xa.w
                           + w3.x*xb.x + w3.y*xb.y + w3.z*xb.z + w3.w*xb.w;
            const float d2 = w4.x*xa.x + w4.y*xa.y + w4.z*xa.z + w4.w*xa.w
                           + w5.x*xb.x + w5.y*xb.y + w5.z*xb.z + w5.w*xb.w;
            const float d3 = w6.x*xa.x + w6.y*xa.y + w6.z*xa.z + w6.w*xa.w
                           + w7.x*xb.x + w7.y*xb.y + w7.z*xb.z + w7.w*xb.w;
            acc[j][0] = fmaf(cwv, d0, acc[j][0]);
            acc[j][1] = fmaf(cwv, d1, acc[j][1]);
            acc[j][2] = fmaf(cwv, d2, acc[j][2]);
            acc[j][3] = fmaf(cwv, d3, acc[j][3]);
        }
    }

    float4* sp4 = (float4*)sp;
    #pragma unroll
    for (int j = 0; j < 4; ++j) {
        const int b = bt * 16 + b4 * 4 + j;
        float4 o4; o4.x = acc[j][0]; o4.y = acc[j][1]; o4.z = acc[j][2]; o4.w = acc[j][3];
        sp4[(rs * B_ + b) * 64 + co4] = o4;
    }
}

// ---------- R: v[b,co] = squash(sum_k sp[k][b][co]); in-block k-split x4 ----------
__global__ __launch_bounds__(1024) void reduce_squash_k(const float* __restrict__ sp,
                                                        float* __restrict__ outv) {
    const int t   = threadIdx.x;
    const int li  = t & 255;
    const int kq  = t >> 8;               // 0..3 k-quarter
    const int idx = blockIdx.x * 256 + li;
    const float* p = sp + (size_t)kq * 32 * 32768 + idx;
    float a0 = 0.f, a1 = 0.f, a2 = 0.f, a3 = 0.f;
    #pragma unroll 8
    for (int k = 0; k < 32; k += 4) {
        a0 += p[(k + 0) * 32768];
        a1 += p[(k + 1) * 32768];
        a2 += p[(k + 2) * 32768];
        a3 += p[(k + 3) * 32768];
    }
    __shared__ float red[1024];
    red[t] = (a0 + a1) + (a2 + a3);
    __syncthreads();
    if (t < 256) {
        const float s = (red[t] + red[t + 256]) + (red[t + 512] + red[t + 768]);
        outv[idx] = squashf(s);
    }
}

// ---------- A: ab[half][c][r] = sum_{b in half, o} u_hat[b,r,co]*v[b,co] ----------
// grid 576 (288 r-groups x 2 halves) x 512. Wave w: rr = w&3, sq = w>>2 (32 b each).
__global__ __launch_bounds__(512) void a_k(const float* __restrict__ x,
                                           const float* __restrict__ W,
                                           const float* __restrict__ v,
                                           float* __restrict__ ab) {
    const int rg   = blockIdx.x >> 1;
    const int half = blockIdx.x & 1;
    const int r0   = rg * 4;
    const int b00  = half * 64;
    const int t    = threadIdx.x;
    const int w    = t >> 6, lane = t & 63;
    const int rr   = w & 3, sq = w >> 2;
    const int co4  = lane, c = lane >> 2;
    const int r    = r0 + rr;

    __shared__ float4 xl[64 * 8];         // x[b00..b00+63][r0..r0+3][0:8] = 8 KB
    __shared__ float  red[128];
    const float4* __restrict__ X4 = (const float4*)x;
    const float4* __restrict__ V4 = (const float4*)v;
    const float4* __restrict__ W4 = (const float4*)W;

    {
        const int bl = t >> 3, rem = t & 7;
        xl[t] = X4[((b00 + bl) * R_ + r0) * 2 + rem];
    }
    __syncthreads();

    float y[8][4];
    #pragma unroll
    for (int i = 0; i < 8; ++i)
        #pragma unroll
        for (int q = 0; q < 4; ++q) y[i][q] = 0.f;

    const int bbase = b00 + sq * 32;
    const int xbase = sq * 32;
    #pragma unroll 4
    for (int bb = 0; bb < 32; ++bb) {
        const float4 xa = xl[(xbase + bb) * 8 + rr * 2];
        const float4 xb = xl[(xbase + bb) * 8 + rr * 2 + 1];
        const float4 vv = V4[(bbase + bb) * 64 + co4];
        const float xs[8] = {xa.x, xa.y, xa.z, xa.w, xb.x, xb.y, xb.z, xb.w};
        #pragma unroll
        for (int i = 0; i < 8; ++i) {
            y[i][0] = fmaf(xs[i], vv.x, y[i][0]);
            y[i][1] = fmaf(xs[i], vv.y, y[i][1]);
            y[i][2] = fmaf(xs[i], vv.z, y[i][2]);
            y[i][3] = fmaf(xs[i], vv.w, y[i][3]);
        }
    }

    // contract with W[r]: part = sum_{q,i} W[r, co4*4+q, i] * y[i][q]
    const int wb = r * 512 + co4 * 8;
    float part = 0.f;
    #pragma unroll
    for (int q = 0; q < 4; ++q) {
        const float4 w0 = W4[wb + q * 2];
        const float4 w1 = W4[wb + q * 2 + 1];
        part += w0.x*y[0][q] + w0.y*y[1][q] + w0.z*y[2][q] + w0.w*y[3][q]
              + w1.x*y[4][q] + w1.y*y[5][q] + w1.z*y[6][q] + w1.w*y[7][q];
    }
    part += __shfl_xor(part, 1);
    part += __shfl_xor(part, 2);
    if ((lane & 3) == 0) red[w * 16 + c] = part;
    __syncthreads();
    if (t < 64) {
        const int rr2 = t >> 4, cc = t & 15;
        // combine sq=0 (w=rr2) and sq=1 (w=rr2+4); store column-major, unscaled
        ab[half * (C_ * R_) + cc * R_ + r0 + rr2] =
            red[rr2 * 16 + cc] + red[(rr2 + 4) * 16 + cc];
    }
}

extern "C" void kernel_launch(void* const* d_in, const int* in_sizes, int n_in,
                              void* d_out, int out_size, void* d_ws, size_t ws_size,
                              hipStream_t stream) {
    const float* x = (const float*)d_in[0];   // [128,1152,8]
    const float* W = (const float*)d_in[1];   // [1,1152,16,16,8]
    float* out = (float*)d_out;               // [128,16,16]
    float* ws  = (float*)d_ws;                // ~17.2 MB used

    float* sp = ws + WS_SP;
    float* v  = ws + WS_V;
    float* ab = ws + WS_AB;                   // [4][16][1152]

    // iter 0 (softmax(0) == 1/R exactly)
    gemm_s_k<0><<<dim3(8, RS_), 256, 0, stream>>>(x, W, ab, sp);
    reduce_squash_k<<<128, 1024, 0, stream>>>(sp, v);
    a_k<<<576, 512, 0, stream>>>(x, W, v, ab);            // writes ab[0..1]

    // iter 1
    gemm_s_k<2><<<dim3(8, RS_), 256, 0, stream>>>(x, W, ab, sp);
    reduce_squash_k<<<128, 1024, 0, stream>>>(sp, v);
    a_k<<<576, 512, 0, stream>>>(x, W, v, ab + 2 * C_ * R_);  // writes ab[2..3]

    // iter 2
    gemm_s_k<4><<<dim3(8, RS_), 256, 0, stream>>>(x, W, ab, sp);
    reduce_squash_k<<<128, 1024, 0, stream>>>(sp, out);
}

// Round 7
// 247.767 us; speedup vs baseline: 1.2699x; 1.0536x over previous
//
#include <hip/hip_runtime.h>
#include <math.h>

#define B_   128
#define R_   1152
#define C_   16
#define O_   16
#define RS_  192
#define RCH_ 6             // R_/RS_

// ws float offsets
#define WS_SP 0            // RS_*32768 = 6291456
#define WS_V  6291456      // 32768
#define WS_AB 6324224      // 4*18432 (ab[h][c][r])

__device__ __forceinline__ float squashf(float s) {
    return s * fabsf(s) / (1.0f + s * s);
}

// ---------- G: sp[rs][b][co] = sum_{r in chunk,i} x[b,r,i]*cw[r,c]*W[r,co,i]
// grid (8 bt, RS_ rs) x 256. W tile staged in LDS transposed [rr][k][co4] so both
// the global stage (coalesced) and the compute read (lane-stride 16B) are optimal.
// NH=0: cw = 1/R (iter 0). NH>0: column softmax of sum_h AB[h][c][r] / B.
template <int NH>
__global__ __launch_bounds__(256) void gemm_s_k(const float* __restrict__ x,
                                                const float* __restrict__ W,
                                                const float* __restrict__ AB,
                                                float* __restrict__ sp) {
    const int bt  = blockIdx.x;
    const int rs  = blockIdx.y;
    const int t   = threadIdx.x;
    const int co4 = t & 63;
    const int b4  = t >> 6;
    const int c   = co4 >> 2;
    const int r0  = rs * RCH_;

    __shared__ float4 wl4[RCH_ * 512];      // 48 KB, transposed W tile
    __shared__ float4 xl4[16 * 2 * RCH_];   // 192 float4 = 3 KB
    __shared__ float  mcs[32];              // [0:16) col max, [16:32) 1/sumexp
    __shared__ float  cwl[RCH_ * 16];       // 96 softmax weights

    const float4* __restrict__ X4 = (const float4*)x;
    const float4* __restrict__ W4 = (const float4*)W;

    // ---- softmax prepass (redundant per block, L2-hot) ----
    if (NH > 0) {
        const int cg = t >> 4, li = t & 15;     // 16 threads per column
        const float* col = AB + cg * R_ + li;
        float m = -1e30f;
        #pragma unroll 4
        for (int k = 0; k < 72; ++k) {
            float s = 0.f;
            #pragma unroll
            for (int h = 0; h < NH; ++h) s += col[h * (C_ * R_) + k * 16];
            m = fmaxf(m, s);
        }
        #pragma unroll
        for (int d = 1; d < 16; d <<= 1) m = fmaxf(m, __shfl_xor(m, d));
        if (li == 0) mcs[cg] = m;
        __syncthreads();
        const float Mc = mcs[cg];
        float e = 0.f;
        #pragma unroll 4
        for (int k = 0; k < 72; ++k) {
            float s = 0.f;
            #pragma unroll
            for (int h = 0; h < NH; ++h) s += col[h * (C_ * R_) + k * 16];
            e += __expf((s - Mc) * (1.0f / (float)B_));
        }
        #pragma unroll
        for (int d = 1; d < 16; d <<= 1) e += __shfl_xor(e, d);
        if (li == 0) mcs[16 + cg] = 1.0f / e;
        __syncthreads();
        if (t < RCH_ * 16) {
            const int rl = t >> 4, cc = t & 15;
            float s = 0.f;
            #pragma unroll
            for (int h = 0; h < NH; ++h) s += AB[h * (C_ * R_) + cc * R_ + r0 + rl];
            cwl[t] = __expf((s - mcs[cc]) * (1.0f / (float)B_)) * mcs[16 + cc];
        }
    }

    // ---- stage W tile, coalesced global -> transposed LDS ----
    #pragma unroll
    for (int kk = 0; kk < 12; ++kk) {
        const int u  = t + kk * 256;            // 0..3071
        const int rr = u >> 9, j = u & 511;
        wl4[rr * 512 + (j & 7) * 64 + (j >> 3)] = W4[r0 * 512 + u];
    }
    // ---- stage x tile (16 b x 6 r x 8 i = 192 float4) ----
    if (t < 192) {
        const int bl = t / 12, rem = t % 12;
        xl4[t] = X4[((bt * 16 + bl) * R_ + r0) * 2 + rem];
    }
    __syncthreads();

    float acc[4][4];
    #pragma unroll
    for (int j = 0; j < 4; ++j)
        #pragma unroll
        for (int q = 0; q < 4; ++q) acc[j][q] = 0.f;

    #pragma unroll 3
    for (int rr = 0; rr < RCH_; ++rr) {
        const float cwv = (NH > 0) ? cwl[rr * 16 + c] : (1.0f / (float)R_);
        const int wb = rr * 512 + co4;          // transposed: + k*64
        const float4 w0 = wl4[wb +   0], w1 = wl4[wb +  64];
        const float4 w2 = wl4[wb + 128], w3 = wl4[wb + 192];
        const float4 w4 = wl4[wb + 256], w5 = wl4[wb + 320];
        const float4 w6 = wl4[wb + 384], w7 = wl4[wb + 448];
        #pragma unroll
        for (int j = 0; j < 4; ++j) {
            const float4 xa = xl4[(b4 * 4 + j) * 12 + rr * 2];
            const float4 xb = xl4[(b4 * 4 + j) * 12 + rr * 2 + 1];
            const float d0 = w0.x*xa.x + w0.y*xa.y + w0.z*xa.z + w0.w*xa.w
                           + w1.x*xb.x + w1.y*xb.y + w1.z*xb.z + w1.w*xb.w;
            const float d1 = w2.x*xa.x + w2.y*xa.y + w2.z*xa.z + w2.w*xa.w
                           + w3.x*xb.x + w3.y*xb.y + w3.z*xb.z + w3.w*xb.w;
            const float d2 = w4.x*xa.x + w4.y*xa.y + w4.z*xa.z + w4.w*xa.w
                           + w5.x*xb.x + w5.y*xb.y + w5.z*xb.z + w5.w*xb.w;
            const float d3 = w6.x*xa.x + w6.y*xa.y + w6.z*xa.z + w6.w*xa.w
                           + w7.x*xb.x + w7.y*xb.y + w7.z*xb.z + w7.w*xb.w;
            acc[j][0] = fmaf(cwv, d0, acc[j][0]);
            acc[j][1] = fmaf(cwv, d1, acc[j][1]);
            acc[j][2] = fmaf(cwv, d2, acc[j][2]);
            acc[j][3] = fmaf(cwv, d3, acc[j][3]);
        }
    }

    float4* sp4 = (float4*)sp;
    #pragma unroll
    for (int j = 0; j < 4; ++j) {
        const int b = bt * 16 + b4 * 4 + j;
        float4 o4; o4.x = acc[j][0]; o4.y = acc[j][1]; o4.z = acc[j][2]; o4.w = acc[j][3];
        sp4[(rs * B_ + b) * 64 + co4] = o4;
    }
}

// ---------- R: v[b,co] = squash(sum_k sp[k][b][co]); in-block k-split x4 ----------
__global__ __launch_bounds__(1024) void reduce_squash_k(const float* __restrict__ sp,
                                                        float* __restrict__ outv) {
    const int t   = threadIdx.x;
    const int li  = t & 255;
    const int kq  = t >> 8;               // 0..3 k-quarter (48 slices each)
    const int idx = blockIdx.x * 256 + li;
    const float* p = sp + (size_t)kq * (RS_ / 4) * 32768 + idx;
    float a0 = 0.f, a1 = 0.f, a2 = 0.f, a3 = 0.f;
    #pragma unroll 6
    for (int k = 0; k < RS_ / 4; k += 4) {
        a0 += p[(k + 0) * 32768];
        a1 += p[(k + 1) * 32768];
        a2 += p[(k + 2) * 32768];
        a3 += p[(k + 3) * 32768];
    }
    __shared__ float red[1024];
    red[t] = (a0 + a1) + (a2 + a3);
    __syncthreads();
    if (t < 256) {
        const float s = (red[t] + red[t + 256]) + (red[t + 512] + red[t + 768]);
        outv[idx] = squashf(s);
    }
}

// ---------- A: ab[half][c][r] = sum_{b in half, o} u_hat[b,r,co]*v[b,co] ----------
// grid 576 (288 r-groups x 2 halves) x 512. W tile (4 r) staged transposed in LDS.
__global__ __launch_bounds__(512) void a_k(const float* __restrict__ x,
                                           const float* __restrict__ W,
                                           const float* __restrict__ v,
                                           float* __restrict__ ab) {
    const int rg   = blockIdx.x >> 1;
    const int half = blockIdx.x & 1;
    const int r0   = rg * 4;
    const int b00  = half * 64;
    const int t    = threadIdx.x;
    const int w    = t >> 6, lane = t & 63;
    const int rr   = w & 3, sq = w >> 2;
    const int co4  = lane, c = lane >> 2;

    __shared__ float4 xl[64 * 8];         // 8 KB
    __shared__ float4 wl[4 * 512];        // 32 KB transposed W tile
    __shared__ float  red[128];
    const float4* __restrict__ X4 = (const float4*)x;
    const float4* __restrict__ V4 = (const float4*)v;
    const float4* __restrict__ W4 = (const float4*)W;

    #pragma unroll
    for (int kk = 0; kk < 4; ++kk) {
        const int u  = t + kk * 512;      // 0..2047
        const int r2 = u >> 9, j = u & 511;
        wl[r2 * 512 + (j & 7) * 64 + (j >> 3)] = W4[r0 * 512 + u];
    }
    {
        const int bl = t >> 3, rem = t & 7;
        xl[t] = X4[((b00 + bl) * R_ + r0) * 2 + rem];
    }
    __syncthreads();

    float y[8][4];
    #pragma unroll
    for (int i = 0; i < 8; ++i)
        #pragma unroll
        for (int q = 0; q < 4; ++q) y[i][q] = 0.f;

    const int bbase = b00 + sq * 32;
    const int xbase = sq * 32;
    #pragma unroll 4
    for (int bb = 0; bb < 32; ++bb) {
        const float4 xa = xl[(xbase + bb) * 8 + rr * 2];
        const float4 xb = xl[(xbase + bb) * 8 + rr * 2 + 1];
        const float4 vv = V4[(bbase + bb) * 64 + co4];
        const float xs[8] = {xa.x, xa.y, xa.z, xa.w, xb.x, xb.y, xb.z, xb.w};
        #pragma unroll
        for (int i = 0; i < 8; ++i) {
            y[i][0] = fmaf(xs[i], vv.x, y[i][0]);
            y[i][1] = fmaf(xs[i], vv.y, y[i][1]);
            y[i][2] = fmaf(xs[i], vv.z, y[i][2]);
            y[i][3] = fmaf(xs[i], vv.w, y[i][3]);
        }
    }

    // contract with W[r] from transposed LDS: float4 for (q,h) at rr*512 + (2q+h)*64 + co4
    const int wb = rr * 512 + co4;
    float part = 0.f;
    #pragma unroll
    for (int q = 0; q < 4; ++q) {
        const float4 w0 = wl[wb + (2 * q) * 64];
        const float4 w1 = wl[wb + (2 * q + 1) * 64];
        part += w0.x*y[0][q] + w0.y*y[1][q] + w0.z*y[2][q] + w0.w*y[3][q]
              + w1.x*y[4][q] + w1.y*y[5][q] + w1.z*y[6][q] + w1.w*y[7][q];
    }
    part += __shfl_xor(part, 1);
    part += __shfl_xor(part, 2);
    if ((lane & 3) == 0) red[w * 16 + c] = part;
    __syncthreads();
    if (t < 64) {
        const int rr2 = t >> 4, cc = t & 15;
        ab[half * (C_ * R_) + cc * R_ + r0 + rr2] =
            red[rr2 * 16 + cc] + red[(rr2 + 4) * 16 + cc];
    }
}

extern "C" void kernel_launch(void* const* d_in, const int* in_sizes, int n_in,
                              void* d_out, int out_size, void* d_ws, size_t ws_size,
                              hipStream_t stream) {
    const float* x = (const float*)d_in[0];   // [128,1152,8]
    const float* W = (const float*)d_in[1];   // [1,1152,16,16,8]
    float* out = (float*)d_out;               // [128,16,16]
    float* ws  = (float*)d_ws;                // ~25.6 MB used

    float* sp = ws + WS_SP;
    float* v  = ws + WS_V;
    float* ab = ws + WS_AB;                   // [4][16][1152]

    // iter 0 (softmax(0) == 1/R exactly)
    gemm_s_k<0><<<dim3(8, RS_), 256, 0, stream>>>(x, W, ab, sp);
    reduce_squash_k<<<128, 1024, 0, stream>>>(sp, v);
    a_k<<<576, 512, 0, stream>>>(x, W, v, ab);                // writes ab[0..1]

    // iter 1
    gemm_s_k<2><<<dim3(8, RS_), 256, 0, stream>>>(x, W, ab, sp);
    reduce_squash_k<<<128, 1024, 0, stream>>>(sp, v);
    a_k<<<576, 512, 0, stream>>>(x, W, v, ab + 2 * C_ * R_);  // writes ab[2..3]

    // iter 2
    gemm_s_k<4><<<dim3(8, RS_), 256, 0, stream>>>(x, W, ab, sp);
    reduce_squash_k<<<128, 1024, 0, stream>>>(sp, out);
}

// Round 8
// 192.929 us; speedup vs baseline: 1.6309x; 1.2842x over previous
//
#include <hip/hip_runtime.h>
#include <math.h>

#define B_   128
#define R_   1152
#define C_   16
#define O_   16
#define RS_  192
#define RCH_ 6             // R_/RS_

// ws float offsets
#define WS_SP   0          // RS_*32768 = 6291456
#define WS_V    6291456    // 32768
#define WS_BLOG 6324224    // 18432
#define WS_CW   6342656    // 18432
#define WS_AB   6361088    // 2*18432 (ab[h][r][c], row-major)

__device__ __forceinline__ float squashf(float s) {
    return s * fabsf(s) / (1.0f + s * s);
}

// ---------- softmax node: blog[r,c] (+)= (ab0+ab1)/B; cw[:,c] = softmax(blog[:,c]) ----
__global__ void softmax_k(float* __restrict__ blog, const float* __restrict__ ab,
                          float* __restrict__ cw, int first) {
    const int c = blockIdx.x;
    const int t = threadIdx.x;
    __shared__ float red[256];

    float m = -1e30f;
    for (int r = t; r < R_; r += 256) {
        const float prev = first ? 0.f : blog[r * C_ + c];
        const float bl = prev + (ab[r * C_ + c] + ab[R_ * C_ + r * C_ + c]) * (1.0f / (float)B_);
        blog[r * C_ + c] = bl;
        m = fmaxf(m, bl);
    }
    red[t] = m; __syncthreads();
    for (int s = 128; s > 0; s >>= 1) {
        if (t < s) red[t] = fmaxf(red[t], red[t + s]);
        __syncthreads();
    }
    const float M = red[0]; __syncthreads();

    float e = 0.f;
    for (int r = t; r < R_; r += 256) e += __expf(blog[r * C_ + c] - M);
    red[t] = e; __syncthreads();
    for (int s = 128; s > 0; s >>= 1) {
        if (t < s) red[t] += red[t + s];
        __syncthreads();
    }
    const float inv = 1.0f / red[0];

    for (int r = t; r < R_; r += 256)
        cw[r * C_ + c] = __expf(blog[r * C_ + c] - M) * inv;
}

// ---------- G: sp[rs][b][co] = sum_{r in chunk,i} x[b,r,i]*cw[r,c]*W[r,co,i]
// grid (8 bt, RS_ rs) x 256. W staged to LDS transposed [rr][k][co4], pitch 65
// (store lanes span all 32 banks; compute reads lane-linear). cw read 1 line/rr.
template <bool USECW>
__global__ __launch_bounds__(256) void gemm_s_k(const float* __restrict__ x,
                                                const float* __restrict__ W,
                                                const float* __restrict__ cw,
                                                float* __restrict__ sp) {
    const int bt  = blockIdx.x;
    const int rs  = blockIdx.y;
    const int t   = threadIdx.x;
    const int co4 = t & 63;
    const int b4  = t >> 6;
    const int c   = co4 >> 2;
    const int r0  = rs * RCH_;

    __shared__ float4 wl4[RCH_ * 520];      // 48.75 KB, pitch-65 transposed W tile
    __shared__ float4 xl4[16 * 2 * RCH_];   // 192 float4 = 3 KB

    const float4* __restrict__ X4 = (const float4*)x;
    const float4* __restrict__ W4 = (const float4*)W;

    // stage W tile: coalesced global read, swizzled LDS store (j = co*8 + k)
    #pragma unroll
    for (int kk = 0; kk < 12; ++kk) {
        const int u  = t + kk * 256;        // 0..3071
        const int rr = u >> 9, j = u & 511;
        wl4[rr * 520 + (j & 7) * 65 + (j >> 3)] = W4[r0 * 512 + u];
    }
    // stage x tile (16 b x 6 r x 8 i = 192 float4)
    if (t < 192) {
        const int bl = t / 12, rem = t % 12;
        xl4[t] = X4[((bt * 16 + bl) * R_ + r0) * 2 + rem];
    }
    __syncthreads();

    float acc[4][4];
    #pragma unroll
    for (int j = 0; j < 4; ++j)
        #pragma unroll
        for (int q = 0; q < 4; ++q) acc[j][q] = 0.f;

    #pragma unroll
    for (int rr = 0; rr < RCH_; ++rr) {
        const float cwv = USECW ? cw[(r0 + rr) * C_ + c] : (1.0f / (float)R_);
        const int wb = rr * 520 + co4;      // + k*65
        const float4 w0 = wl4[wb +   0], w1 = wl4[wb +  65];
        const float4 w2 = wl4[wb + 130], w3 = wl4[wb + 195];
        const float4 w4 = wl4[wb + 260], w5 = wl4[wb + 325];
        const float4 w6 = wl4[wb + 390], w7 = wl4[wb + 455];
        #pragma unroll
        for (int j = 0; j < 4; ++j) {
            const float4 xa = xl4[(b4 * 4 + j) * 12 + rr * 2];
            const float4 xb = xl4[(b4 * 4 + j) * 12 + rr * 2 + 1];
            const float d0 = w0.x*xa.x + w0.y*xa.y + w0.z*xa.z + w0.w*xa.w
                           + w1.x*xb.x + w1.y*xb.y + w1.z*xb.z + w1.w*xb.w;
            const float d1 = w2.x*xa.x + w2.y*xa.y + w2.z*xa.z + w2.w*xa.w
                           + w3.x*xb.x + w3.y*xb.y + w3.z*xb.z + w3.w*xb.w;
            const float d2 = w4.x*xa.x + w4.y*xa.y + w4.z*xa.z + w4.w*xa.w
                           + w5.x*xb.x + w5.y*xb.y + w5.z*xb.z + w5.w*xb.w;
            const float d3 = w6.x*xa.x + w6.y*xa.y + w6.z*xa.z + w6.w*xa.w
                           + w7.x*xb.x + w7.y*xb.y + w7.z*xb.z + w7.w*xb.w;
            acc[j][0] = fmaf(cwv, d0, acc[j][0]);
            acc[j][1] = fmaf(cwv, d1, acc[j][1]);
            acc[j][2] = fmaf(cwv, d2, acc[j][2]);
            acc[j][3] = fmaf(cwv, d3, acc[j][3]);
        }
    }

    float4* sp4 = (float4*)sp;
    #pragma unroll
    for (int j = 0; j < 4; ++j) {
        const int b = bt * 16 + b4 * 4 + j;
        float4 o4; o4.x = acc[j][0]; o4.y = acc[j][1]; o4.z = acc[j][2]; o4.w = acc[j][3];
        sp4[(rs * B_ + b) * 64 + co4] = o4;
    }
}

// ---------- R: v[b,co] = squash(sum_k sp[k][b][co]); in-block k-split x4 ----------
__global__ __launch_bounds__(1024) void reduce_squash_k(const float* __restrict__ sp,
                                                        float* __restrict__ outv) {
    const int t   = threadIdx.x;
    const int li  = t & 255;
    const int kq  = t >> 8;               // 0..3 k-quarter (48 slices each)
    const int idx = blockIdx.x * 256 + li;
    const float* p = sp + (size_t)kq * (RS_ / 4) * 32768 + idx;
    float a0 = 0.f, a1 = 0.f, a2 = 0.f, a3 = 0.f;
    #pragma unroll 6
    for (int k = 0; k < RS_ / 4; k += 4) {
        a0 += p[(k + 0) * 32768];
        a1 += p[(k + 1) * 32768];
        a2 += p[(k + 2) * 32768];
        a3 += p[(k + 3) * 32768];
    }
    __shared__ float red[1024];
    red[t] = (a0 + a1) + (a2 + a3);
    __syncthreads();
    if (t < 256) {
        const float s = (red[t] + red[t + 256]) + (red[t + 512] + red[t + 768]);
        outv[idx] = squashf(s);
    }
}

// ---------- A: ab[half][r][c] = sum_{b in half, o} u_hat[b,r,co]*v[b,co] ----------
// grid 576 (288 r-groups x 2 halves) x 512. W tile staged transposed, pitch 65.
__global__ __launch_bounds__(512) void a_k(const float* __restrict__ x,
                                           const float* __restrict__ W,
                                           const float* __restrict__ v,
                                           float* __restrict__ ab) {
    const int rg   = blockIdx.x >> 1;
    const int half = blockIdx.x & 1;
    const int r0   = rg * 4;
    const int b00  = half * 64;
    const int t    = threadIdx.x;
    const int w    = t >> 6, lane = t & 63;
    const int rr   = w & 3, sq = w >> 2;
    const int co4  = lane, c = lane >> 2;

    __shared__ float4 xl[64 * 8];         // 8 KB
    __shared__ float4 wl[4 * 520];        // 33.3 KB, pitch-65 transposed
    __shared__ float  red[128];
    const float4* __restrict__ X4 = (const float4*)x;
    const float4* __restrict__ V4 = (const float4*)v;
    const float4* __restrict__ W4 = (const float4*)W;

    #pragma unroll
    for (int kk = 0; kk < 4; ++kk) {
        const int u  = t + kk * 512;      // 0..2047
        const int r2 = u >> 9, j = u & 511;
        wl[r2 * 520 + (j & 7) * 65 + (j >> 3)] = W4[r0 * 512 + u];
    }
    {
        const int bl = t >> 3, rem = t & 7;
        xl[t] = X4[((b00 + bl) * R_ + r0) * 2 + rem];
    }
    __syncthreads();

    float y[8][4];
    #pragma unroll
    for (int i = 0; i < 8; ++i)
        #pragma unroll
        for (int q = 0; q < 4; ++q) y[i][q] = 0.f;

    const int bbase = b00 + sq * 32;
    const int xbase = sq * 32;
    #pragma unroll 4
    for (int bb = 0; bb < 32; ++bb) {
        const float4 xa = xl[(xbase + bb) * 8 + rr * 2];
        const float4 xb = xl[(xbase + bb) * 8 + rr * 2 + 1];
        const float4 vv = V4[(bbase + bb) * 64 + co4];
        const float xs[8] = {xa.x, xa.y, xa.z, xa.w, xb.x, xb.y, xb.z, xb.w};
        #pragma unroll
        for (int i = 0; i < 8; ++i) {
            y[i][0] = fmaf(xs[i], vv.x, y[i][0]);
            y[i][1] = fmaf(xs[i], vv.y, y[i][1]);
            y[i][2] = fmaf(xs[i], vv.z, y[i][2]);
            y[i][3] = fmaf(xs[i], vv.w, y[i][3]);
        }
    }

    // contract with W[r]: float4 for (q,h) at rr*520 + (2q+h)*65 + co4
    const int wb = rr * 520 + co4;
    float part = 0.f;
    #pragma unroll
    for (int q = 0; q < 4; ++q) {
        const float4 w0 = wl[wb + (2 * q) * 65];
        const float4 w1 = wl[wb + (2 * q + 1) * 65];
        part += w0.x*y[0][q] + w0.y*y[1][q] + w0.z*y[2][q] + w0.w*y[3][q]
              + w1.x*y[4][q] + w1.y*y[5][q] + w1.z*y[6][q] + w1.w*y[7][q];
    }
    part += __shfl_xor(part, 1);
    part += __shfl_xor(part, 2);
    if ((lane & 3) == 0) red[w * 16 + c] = part;
    __syncthreads();
    if (t < 64) {
        const int rr2 = t >> 4, cc = t & 15;
        ab[half * (R_ * C_) + (r0 + rr2) * C_ + cc] =
            red[rr2 * 16 + cc] + red[(rr2 + 4) * 16 + cc];
    }
}

extern "C" void kernel_launch(void* const* d_in, const int* in_sizes, int n_in,
                              void* d_out, int out_size, void* d_ws, size_t ws_size,
                              hipStream_t stream) {
    const float* x = (const float*)d_in[0];   // [128,1152,8]
    const float* W = (const float*)d_in[1];   // [1,1152,16,16,8]
    float* out = (float*)d_out;               // [128,16,16]
    float* ws  = (float*)d_ws;                // ~25.6 MB used

    float* sp   = ws + WS_SP;
    float* v    = ws + WS_V;
    float* blog = ws + WS_BLOG;
    float* cw   = ws + WS_CW;
    float* ab   = ws + WS_AB;

    // iter 0 (softmax(0) == 1/R exactly; no cw needed)
    gemm_s_k<false><<<dim3(8, RS_), 256, 0, stream>>>(x, W, cw, sp);
    reduce_squash_k<<<128, 1024, 0, stream>>>(sp, v);
    a_k<<<576, 512, 0, stream>>>(x, W, v, ab);

    // iter 1
    softmax_k<<<C_, 256, 0, stream>>>(blog, ab, cw, 1);
    gemm_s_k<true><<<dim3(8, RS_), 256, 0, stream>>>(x, W, cw, sp);
    reduce_squash_k<<<128, 1024, 0, stream>>>(sp, v);
    a_k<<<576, 512, 0, stream>>>(x, W, v, ab);

    // iter 2
    softmax_k<<<C_, 256, 0, stream>>>(blog, ab, cw, 0);
    gemm_s_k<true><<<dim3(8, RS_), 256, 0, stream>>>(x, W, cw, sp);
    reduce_squash_k<<<128, 1024, 0, stream>>>(sp, out);
}